// Round 6
// baseline (533.168 us; speedup 1.0000x reference)
//
#include <hip/hip_runtime.h>

typedef unsigned short u16;
typedef unsigned int   u32;
typedef __attribute__((ext_vector_type(8))) short bf16x8;   // 8 bf16 in 4 VGPRs
typedef __attribute__((ext_vector_type(4))) float f32x4;

#define S_LEN 2048
#define EMB   1024
#define NH    16
#define HD    64
#define FF_DIM 4096
#define NROWS 4096   // B*S

__device__ __forceinline__ float b2f(u16 u){ union{u32 i; float f;} c; c.i = ((u32)u)<<16; return c.f; }
__device__ __forceinline__ u16 f2b(float f){ union{float f; u32 u;} c; c.f=f; u32 r = c.u + 0x7fffu + ((c.u>>16)&1u); return (u16)(r>>16); }
__device__ __forceinline__ float gelu_f(float x){ return 0.5f*x*(1.0f + erff(x*0.70710678118f)); }

// async global->LDS, 16B per lane; lds dest = wave-uniform base + lane*16 (m97/m104)
__device__ __forceinline__ void load_lds16(const u16* g, u16* l) {
    __builtin_amdgcn_global_load_lds((const __attribute__((address_space(1))) u32*)g,
                                     (__attribute__((address_space(3))) u32*)l, 16, 0, 0);
}

// ---------------------------------------------------------------- LayerNorm
template<int XF32>
__global__ __launch_bounds__(256)
void ln_kernel(const void* __restrict__ Xv, const float* __restrict__ G,
               const float* __restrict__ Bv, u16* __restrict__ Y)
{
    const int row = blockIdx.x, t = threadIdx.x;
    float v0, v1, v2, v3;
    if constexpr (XF32) {
        float4 r4 = ((const float4*)((const float*)Xv + (size_t)row*EMB))[t];
        v0 = r4.x; v1 = r4.y; v2 = r4.z; v3 = r4.w;
    } else {
        const u16* xr = (const u16*)Xv + (size_t)row*EMB;
        uint2 raw = *(const uint2*)(xr + t*4);
        v0 = b2f(raw.x & 0xffff); v1 = b2f(raw.x >> 16);
        v2 = b2f(raw.y & 0xffff); v3 = b2f(raw.y >> 16);
    }
    float s  = v0+v1+v2+v3;
    float s2 = v0*v0+v1*v1+v2*v2+v3*v3;
    #pragma unroll
    for (int off = 1; off < 64; off <<= 1) {
        s  += __shfl_xor(s,  off, 64);
        s2 += __shfl_xor(s2, off, 64);
    }
    __shared__ float ps[4], ps2[4];
    const int w = t >> 6, lane = t & 63;
    if (lane == 0) { ps[w] = s; ps2[w] = s2; }
    __syncthreads();
    s  = ps[0]+ps[1]+ps[2]+ps[3];
    s2 = ps2[0]+ps2[1]+ps2[2]+ps2[3];
    const float mu   = s * (1.0f/EMB);
    const float rstd = rsqrtf(fmaxf(s2*(1.0f/EMB) - mu*mu, 0.f) + 1e-5f);
    float4 g4 = ((const float4*)G)[t];
    float4 c4 = ((const float4*)Bv)[t];
    u32 lo = (u32)f2b((v0-mu)*rstd*g4.x + c4.x) | ((u32)f2b((v1-mu)*rstd*g4.y + c4.y) << 16);
    u32 hi = (u32)f2b((v2-mu)*rstd*g4.z + c4.z) | ((u32)f2b((v3-mu)*rstd*g4.w + c4.w) << 16);
    uint2 o; o.x = lo; o.y = hi;
    *(uint2*)(Y + (size_t)row*EMB + t*4) = o;
}

// ---------------------------------------------------------------- transpose+downconvert (f32 [K][N] -> bf16 [N][K])
__global__ __launch_bounds__(256)
void transpose_k(const float* __restrict__ in, u16* __restrict__ out, int K, int N)
{
    __shared__ __align__(16) u16 T[64*72];
    const int k0 = blockIdx.y*64, n0 = blockIdx.x*64, t = threadIdx.x;
    #pragma unroll
    for (int c = 0; c < 4; ++c) {
        int e = t*4 + c*1024, ki = e >> 6, nj = e & 63;
        float4 f = *(const float4*)(in + (size_t)(k0+ki)*N + n0 + nj);
        ushort4 s4; s4.x = f2b(f.x); s4.y = f2b(f.y); s4.z = f2b(f.z); s4.w = f2b(f.w);
        *(ushort4*)&T[ki*72 + nj] = s4;
    }
    __syncthreads();
    #pragma unroll
    for (int c = 0; c < 2; ++c) {
        int e = t*8 + c*2048, ni = e >> 6, kj = e & 63;
        uint4 v; u16* pv = (u16*)&v;
        #pragma unroll
        for (int j = 0; j < 8; ++j) pv[j] = T[(kj+j)*72 + ni];
        *(uint4*)(out + (size_t)(n0+ni)*K + k0 + kj) = v;
    }
}

// ---------------------------------------------------------------- GEMM: C = A @ Bt^T + bias (m97-style staging)
// MODE 0: plain  1: +res  2: gelu  5: fused QKV split (C=Q,C2=K head-split; C3=V head-split-T)
// RESF: res f32(1)/bf16(0).  OUTF: C f32(1)/bf16(0).
template<int MODE, int RESF, int OUTF>
__global__ __launch_bounds__(256)
void gemm_bt(const u16* __restrict__ A, const u16* __restrict__ Bt,
             const float* __restrict__ bias, const float* __restrict__ bias2,
             const float* __restrict__ bias3, const void* __restrict__ res,
             void* __restrict__ C, void* __restrict__ C2, void* __restrict__ C3,
             int M, int N, int K)
{
    __shared__ __align__(16) u16 As[128*32];
    __shared__ __align__(16) u16 Bs[128*32];
    const int t = threadIdx.x;
    const int m0 = blockIdx.y*128, n0 = blockIdx.x*128;
    const int wave = t >> 6, lane = t & 63;
    const int wm = (wave >> 1)*64, wn = (wave & 1)*64;
    const int lr = lane & 15, quad = lane >> 4;

    const int srow = wave*16 + (lane >> 2);
    const int scol = (lane & 3)*8;
    const u16* gA = A  + (size_t)(m0 + srow)*K + scol;
    const u16* gB = Bt + (size_t)(n0 + srow)*K + scol;
    u16* lA = &As[wave*16*32];
    u16* lB = &Bs[wave*16*32];

    f32x4 acc[4][4];
    const f32x4 fzero = {0.f, 0.f, 0.f, 0.f};
    #pragma unroll
    for (int mt = 0; mt < 4; ++mt)
        #pragma unroll
        for (int nt = 0; nt < 4; ++nt) acc[mt][nt] = fzero;

    for (int kt = 0; kt < K; kt += 32) {
        __syncthreads();
        load_lds16(gA,                lA);
        load_lds16(gA + (size_t)64*K, lA + 64*32);
        load_lds16(gB,                lB);
        load_lds16(gB + (size_t)64*K, lB + 64*32);
        gA += 32; gB += 32;
        __syncthreads();
        bf16x8 af[4], bf[4];
        #pragma unroll
        for (int i = 0; i < 4; ++i) {
            af[i] = *(const bf16x8*)&As[(wm + i*16 + lr)*32 + quad*8];
            bf[i] = *(const bf16x8*)&Bs[(wn + i*16 + lr)*32 + quad*8];
        }
        #pragma unroll
        for (int mt = 0; mt < 4; ++mt)
            #pragma unroll
            for (int nt = 0; nt < 4; ++nt)
                acc[mt][nt] = __builtin_amdgcn_mfma_f32_16x16x32_bf16(af[mt], bf[nt], acc[mt][nt], 0, 0, 0);
    }

    #pragma unroll
    for (int nt = 0; nt < 4; ++nt) {
        int col = n0 + wn + nt*16 + lr;
        float bval;
        if constexpr (MODE == 5) {
            int seg = col >> 10, cs = col & 1023;
            bval = (seg == 0 ? bias : (seg == 1 ? bias2 : bias3))[cs];
        } else {
            bval = bias[col];
        }
        #pragma unroll
        for (int mt = 0; mt < 4; ++mt) {
            #pragma unroll
            for (int r = 0; r < 4; ++r) {
                int row = m0 + wm + mt*16 + quad*4 + r;
                float v = acc[mt][nt][r] + bval;
                if constexpr (MODE == 1) {
                    if constexpr (RESF) v += ((const float*)res)[(size_t)row*N + col];
                    else                v += b2f(((const u16*)res)[(size_t)row*N + col]);
                }
                if constexpr (MODE == 2) v = gelu_f(v);
                if constexpr (MODE == 5) {
                    int seg = col >> 10, cs = col & 1023;
                    int b = row >> 11, s = row & 2047, h = cs >> 6, d = cs & 63;
                    if (seg < 2) {
                        u16* dst = (u16*)(seg == 0 ? C : C2);
                        dst[(((size_t)(b*NH + h)*S_LEN + s) << 6) + d] = f2b(v);
                    } else {
                        ((u16*)C3)[(((size_t)(b*NH + h)*HD + d) << 11) + s] = f2b(v);
                    }
                } else {
                    size_t idx = (size_t)row*N + col;
                    if constexpr (OUTF) ((float*)C)[idx] = v;
                    else                ((u16*)C)[idx]   = f2b(v);
                }
            }
        }
    }
}

// ---------------------------------------------------------------- attention (causal)
// Wave-per-Q-split: each wave owns 16 q rows x full causal K range. Zero barriers,
// no cross-wave combine, LDS = wave-private P buffer only (9.2 KB -> 4 blocks/CU).
// Q,K: [B*H][S][64]; Vt: [B*H][64][S]; O: [B][S][1024]
__global__ __launch_bounds__(256, 4)
void attn_kernel(const u16* __restrict__ Q, const u16* __restrict__ Kg,
                 const u16* __restrict__ Vt, u16* __restrict__ O)
{
    const int bh = blockIdx.y;
    const int qt = (blockIdx.x + bh) & 31;        // swizzle: balance causal load across CUs
    const int t = threadIdx.x, wave = t >> 6, lane = t & 63;
    const int lr = lane & 15, quad = lane >> 4;

    __shared__ __align__(16) u16 Ps[4][16*72];    // 9216 B total

    const size_t qkbase = (size_t)bh * (S_LEN*HD);
    const int qrow0 = qt*64 + wave*16;

    // Q fragments (16 rows per wave) direct from global
    const u16* qp = Q + qkbase + (size_t)(qrow0 + lr)*HD + quad*8;
    bf16x8 qf0 = *(const bf16x8*)qp;
    bf16x8 qf1 = *(const bf16x8*)(qp + 32);

    f32x4 oacc[4];
    float lpart[4];
    const f32x4 fzero = {0.f, 0.f, 0.f, 0.f};
    #pragma unroll
    for (int dt = 0; dt < 4; ++dt) oacc[dt] = fzero;
    #pragma unroll
    for (int r = 0; r < 4; ++r) lpart[r] = 0.f;

    u16* Pw = Ps[wave];
    const int qrowq = qrow0 + quad*4;

    for (int kb = 0; kb <= qt; ++kb) {
        // QK^T: 16 q x 64 k
        f32x4 sc[4];
        #pragma unroll
        for (int kt2 = 0; kt2 < 4; ++kt2) {
            const u16* kp = Kg + qkbase + (size_t)(kb*64 + kt2*16 + lr)*HD + quad*8;
            bf16x8 kf0 = *(const bf16x8*)kp;
            bf16x8 kf1 = *(const bf16x8*)(kp + 32);
            sc[kt2] = __builtin_amdgcn_mfma_f32_16x16x32_bf16(qf0, kf0, fzero, 0, 0, 0);
            sc[kt2] = __builtin_amdgcn_mfma_f32_16x16x32_bf16(qf1, kf1, sc[kt2], 0, 0, 0);
        }
        const bool diag = (kb == qt);
        #pragma unroll
        for (int r = 0; r < 4; ++r) {
            #pragma unroll
            for (int kt2 = 0; kt2 < 4; ++kt2) {
                int kcol = kb*64 + kt2*16 + lr;
                float p = (!diag || kcol <= qrowq + r) ? __expf(fminf(sc[kt2][r]*0.125f, 30.f)) : 0.f;
                lpart[r] += p;
                Pw[(quad*4 + r)*72 + kt2*16 + lr] = f2b(p);
            }
        }
        // PV (P via wave-private LDS round-trip; same-wave LDS ops are in-order)
        bf16x8 pf0 = *(const bf16x8*)&Pw[lr*72 + quad*8];
        bf16x8 pf1 = *(const bf16x8*)&Pw[lr*72 + 32 + quad*8];
        #pragma unroll
        for (int dt = 0; dt < 4; ++dt) {
            const u16* vp = Vt + qkbase + (size_t)(dt*16 + lr)*S_LEN + kb*64 + quad*8;
            bf16x8 vf0 = *(const bf16x8*)vp;
            bf16x8 vf1 = *(const bf16x8*)(vp + 32);
            oacc[dt] = __builtin_amdgcn_mfma_f32_16x16x32_bf16(pf0, vf0, oacc[dt], 0, 0, 0);
            oacc[dt] = __builtin_amdgcn_mfma_f32_16x16x32_bf16(pf1, vf1, oacc[dt], 0, 0, 0);
        }
    }

    // fold lpart across the 16 lr lanes
    #pragma unroll
    for (int r = 0; r < 4; ++r) {
        float v = lpart[r];
        v += __shfl_xor(v, 1, 64); v += __shfl_xor(v, 2, 64);
        v += __shfl_xor(v, 4, 64); v += __shfl_xor(v, 8, 64);
        lpart[r] = 1.0f / fmaxf(v, 1e-20f);
    }

    // stage output tile (16x64 bf16) through dead P space, then 16B stores
    #pragma unroll
    for (int dt = 0; dt < 4; ++dt)
        #pragma unroll
        for (int r = 0; r < 4; ++r)
            Pw[(quad*4 + r)*64 + dt*16 + lr] = f2b(oacc[dt][r] * lpart[r]);

    const int b = bh >> 4, h = bh & 15;
    const int q = lane >> 2, d0 = (lane & 3)*16;
    u16* dst = O + ((size_t)(b*S_LEN + qrow0 + q))*EMB + h*HD + d0;
    *(uint4*)(dst)     = *(uint4*)&Pw[q*64 + d0];
    *(uint4*)(dst + 8) = *(uint4*)&Pw[q*64 + d0 + 8];
}

// ---------------------------------------------------------------- launch
extern "C" void kernel_launch(void* const* d_in, const int* in_sizes, int n_in,
                              void* d_out, int out_size, void* d_ws, size_t ws_size,
                              hipStream_t stream)
{
    (void)in_sizes; (void)n_in; (void)out_size; (void)ws_size;
    const float* x    = (const float*)d_in[0];
    // d_in[1] = mask: causal tril, handled analytically
    const float* ln1g = (const float*)d_in[2];
    const float* ln1b = (const float*)d_in[3];
    const float* wq = (const float*)d_in[4];  const float* bq = (const float*)d_in[5];
    const float* wk = (const float*)d_in[6];  const float* bk = (const float*)d_in[7];
    const float* wv = (const float*)d_in[8];  const float* bv = (const float*)d_in[9];
    const float* wo = (const float*)d_in[10]; const float* bo = (const float*)d_in[11];
    const float* ln2g = (const float*)d_in[12]; const float* ln2b = (const float*)d_in[13];
    const float* w1 = (const float*)d_in[14]; const float* b1 = (const float*)d_in[15];
    const float* w2 = (const float*)d_in[16]; const float* b2 = (const float*)d_in[17];

    u16* ws = (u16*)d_ws;
    const size_t M1 = 1u << 20;             // 1M u16 elements (2 MB)
    u16* wqkvT = ws + 0*M1;                 // bf16 [3072][1024] = wqT|wkT|wvT contiguous
    u16* wqT = ws + 0*M1;
    u16* wkT = ws + 1*M1;
    u16* wvT = ws + 2*M1;
    u16* woT = ws + 3*M1;
    u16* w2T = ws + 0*M1;                   // bf16 [1024][4096], transposed AFTER wo-gemm
    u16* w1T = ws + 4*M1;                   // bf16 [4096][1024]
    u16* h0  = ws + 8*M1;                   // bf16 ln out (reused for ln2 out)
    u16* qb  = ws + 12*M1;                  // bf16 [B,H,S,D]
    u16* kb  = ws + 16*M1;                  // bf16 [B,H,S,D]
    u16* vT  = ws + 20*M1;                  // bf16 [B,H,D,S]
    u16* ao  = ws + 24*M1;                  // bf16 attn out [B,S,E]
    u16* x1  = ws + 28*M1;                  // bf16 residual-1 out
    u16* fb  = ws + 12*M1;                  // bf16 MLP hidden, overlays q/k/v/ao (dead)

    dim3 blk(256);
    transpose_k<<<dim3(16,16), blk, 0, stream>>>(wq, wqT, EMB, EMB);
    transpose_k<<<dim3(16,16), blk, 0, stream>>>(wk, wkT, EMB, EMB);
    transpose_k<<<dim3(16,16), blk, 0, stream>>>(wv, wvT, EMB, EMB);
    transpose_k<<<dim3(16,16), blk, 0, stream>>>(wo, woT, EMB, EMB);
    transpose_k<<<dim3(64,16), blk, 0, stream>>>(w1, w1T, EMB, FF_DIM);

    ln_kernel<1><<<NROWS, blk, 0, stream>>>(x, ln1g, ln1b, h0);

    gemm_bt<5,0,0><<<dim3(24,32), blk, 0, stream>>>(h0, wqkvT, bq, bk, bv, nullptr,
                                                    qb, kb, vT, NROWS, 3072, EMB);

    attn_kernel<<<dim3(32,32), blk, 0, stream>>>(qb, kb, vT, ao);

    gemm_bt<1,1,0><<<dim3(8,32),  blk, 0, stream>>>(ao, woT, bo, nullptr, nullptr, x,
                                                    x1, nullptr, nullptr, NROWS, EMB, EMB);

    transpose_k<<<dim3(16,64), blk, 0, stream>>>(w2, w2T, FF_DIM, EMB);

    ln_kernel<0><<<NROWS, blk, 0, stream>>>(x1, ln2g, ln2b, h0);

    gemm_bt<2,0,0><<<dim3(32,32), blk, 0, stream>>>(h0, w1T, b1, nullptr, nullptr, nullptr,
                                                    fb, nullptr, nullptr, NROWS, FF_DIM, EMB);
    gemm_bt<1,0,1><<<dim3(8,32),  blk, 0, stream>>>(fb, w2T, b2, nullptr, nullptr, x1,
                                                    d_out, nullptr, nullptr, NROWS, EMB, FF_DIM);
}

// Round 7
// 505.638 us; speedup vs baseline: 1.0544x; 1.0544x over previous
//
#include <hip/hip_runtime.h>

typedef unsigned short u16;
typedef unsigned int   u32;
typedef __attribute__((ext_vector_type(8))) short bf16x8;   // 8 bf16 in 4 VGPRs
typedef __attribute__((ext_vector_type(4))) float f32x4;

#define S_LEN 2048
#define EMB   1024
#define NH    16
#define HD    64
#define FF_DIM 4096
#define NROWS 4096   // B*S

__device__ __forceinline__ float b2f(u16 u){ union{u32 i; float f;} c; c.i = ((u32)u)<<16; return c.f; }
__device__ __forceinline__ u16 f2b(float f){ union{float f; u32 u;} c; c.f=f; u32 r = c.u + 0x7fffu + ((c.u>>16)&1u); return (u16)(r>>16); }
__device__ __forceinline__ float gelu_f(float x){ return 0.5f*x*(1.0f + erff(x*0.70710678118f)); }

// async global->LDS, 16B per lane; lds dest = wave-uniform base + lane*16 (m97/m104)
__device__ __forceinline__ void load_lds16(const u16* g, u16* l) {
    __builtin_amdgcn_global_load_lds((const __attribute__((address_space(1))) u32*)g,
                                     (__attribute__((address_space(3))) u32*)l, 16, 0, 0);
}

// ---------------------------------------------------------------- LayerNorm
template<int XF32>
__global__ __launch_bounds__(256)
void ln_kernel(const void* __restrict__ Xv, const float* __restrict__ G,
               const float* __restrict__ Bv, u16* __restrict__ Y)
{
    const int row = blockIdx.x, t = threadIdx.x;
    float v0, v1, v2, v3;
    if constexpr (XF32) {
        float4 r4 = ((const float4*)((const float*)Xv + (size_t)row*EMB))[t];
        v0 = r4.x; v1 = r4.y; v2 = r4.z; v3 = r4.w;
    } else {
        const u16* xr = (const u16*)Xv + (size_t)row*EMB;
        uint2 raw = *(const uint2*)(xr + t*4);
        v0 = b2f(raw.x & 0xffff); v1 = b2f(raw.x >> 16);
        v2 = b2f(raw.y & 0xffff); v3 = b2f(raw.y >> 16);
    }
    float s  = v0+v1+v2+v3;
    float s2 = v0*v0+v1*v1+v2*v2+v3*v3;
    #pragma unroll
    for (int off = 1; off < 64; off <<= 1) {
        s  += __shfl_xor(s,  off, 64);
        s2 += __shfl_xor(s2, off, 64);
    }
    __shared__ float ps[4], ps2[4];
    const int w = t >> 6, lane = t & 63;
    if (lane == 0) { ps[w] = s; ps2[w] = s2; }
    __syncthreads();
    s  = ps[0]+ps[1]+ps[2]+ps[3];
    s2 = ps2[0]+ps2[1]+ps2[2]+ps2[3];
    const float mu   = s * (1.0f/EMB);
    const float rstd = rsqrtf(fmaxf(s2*(1.0f/EMB) - mu*mu, 0.f) + 1e-5f);
    float4 g4 = ((const float4*)G)[t];
    float4 c4 = ((const float4*)Bv)[t];
    u32 lo = (u32)f2b((v0-mu)*rstd*g4.x + c4.x) | ((u32)f2b((v1-mu)*rstd*g4.y + c4.y) << 16);
    u32 hi = (u32)f2b((v2-mu)*rstd*g4.z + c4.z) | ((u32)f2b((v3-mu)*rstd*g4.w + c4.w) << 16);
    uint2 o; o.x = lo; o.y = hi;
    *(uint2*)(Y + (size_t)row*EMB + t*4) = o;
}

// ---------------------------------------------------------------- transpose+downconvert (f32 [K][N] -> bf16 [N][K])
__global__ __launch_bounds__(256)
void transpose_k(const float* __restrict__ in, u16* __restrict__ out, int K, int N)
{
    __shared__ __align__(16) u16 T[64*72];
    const int k0 = blockIdx.y*64, n0 = blockIdx.x*64, t = threadIdx.x;
    #pragma unroll
    for (int c = 0; c < 4; ++c) {
        int e = t*4 + c*1024, ki = e >> 6, nj = e & 63;
        float4 f = *(const float4*)(in + (size_t)(k0+ki)*N + n0 + nj);
        ushort4 s4; s4.x = f2b(f.x); s4.y = f2b(f.y); s4.z = f2b(f.z); s4.w = f2b(f.w);
        *(ushort4*)&T[ki*72 + nj] = s4;
    }
    __syncthreads();
    #pragma unroll
    for (int c = 0; c < 2; ++c) {
        int e = t*8 + c*2048, ni = e >> 6, kj = e & 63;
        uint4 v; u16* pv = (u16*)&v;
        #pragma unroll
        for (int j = 0; j < 8; ++j) pv[j] = T[(kj+j)*72 + ni];
        *(uint4*)(out + (size_t)(n0+ni)*K + k0 + kj) = v;
    }
}

// ---------------------------------------------------------------- bf16 transpose: V [B*H][S][64] -> V^T [B*H][64][S]
__global__ __launch_bounds__(256)
void vtrans(const u16* __restrict__ in, u16* __restrict__ out)
{
    __shared__ __align__(16) u16 T[64*72];
    const int bh = blockIdx.y, s0 = blockIdx.x*64, t = threadIdx.x;
    const size_t base = (size_t)bh * (S_LEN*HD);
    #pragma unroll
    for (int c = 0; c < 2; ++c) {
        int e = t*8 + c*2048, r = e >> 6, d = e & 63;
        *(uint4*)&T[r*72 + d] = *(const uint4*)(in + base + (size_t)(s0 + r)*HD + d);
    }
    __syncthreads();
    #pragma unroll
    for (int c = 0; c < 2; ++c) {
        int e = t*8 + c*2048, d = e >> 6, sj = e & 63;
        uint4 v; u16* pv = (u16*)&v;
        #pragma unroll
        for (int j = 0; j < 8; ++j) pv[j] = T[(sj + j)*72 + d];
        *(uint4*)(out + base + (size_t)d*S_LEN + s0 + sj) = v;
    }
}

// ---------------------------------------------------------------- GEMM: C = A @ Bt^T + bias (m97-style staging)
// MODE 0: plain  1: +res  2: gelu  5: fused QKV (C=Q,C2=K,C3=V, all head-split [B,H,S,D])
// RESF: res f32(1)/bf16(0).  OUTF: C f32(1)/bf16(0).
template<int MODE, int RESF, int OUTF>
__global__ __launch_bounds__(256)
void gemm_bt(const u16* __restrict__ A, const u16* __restrict__ Bt,
             const float* __restrict__ bias, const float* __restrict__ bias2,
             const float* __restrict__ bias3, const void* __restrict__ res,
             void* __restrict__ C, void* __restrict__ C2, void* __restrict__ C3,
             int M, int N, int K)
{
    __shared__ __align__(16) u16 As[128*32];
    __shared__ __align__(16) u16 Bs[128*32];
    const int t = threadIdx.x;
    const int m0 = blockIdx.y*128, n0 = blockIdx.x*128;
    const int wave = t >> 6, lane = t & 63;
    const int wm = (wave >> 1)*64, wn = (wave & 1)*64;
    const int lr = lane & 15, quad = lane >> 4;

    const int srow = wave*16 + (lane >> 2);
    const int scol = (lane & 3)*8;
    const u16* gA = A  + (size_t)(m0 + srow)*K + scol;
    const u16* gB = Bt + (size_t)(n0 + srow)*K + scol;
    u16* lA = &As[wave*16*32];
    u16* lB = &Bs[wave*16*32];

    f32x4 acc[4][4];
    const f32x4 fzero = {0.f, 0.f, 0.f, 0.f};
    #pragma unroll
    for (int mt = 0; mt < 4; ++mt)
        #pragma unroll
        for (int nt = 0; nt < 4; ++nt) acc[mt][nt] = fzero;

    for (int kt = 0; kt < K; kt += 32) {
        __syncthreads();
        load_lds16(gA,                lA);
        load_lds16(gA + (size_t)64*K, lA + 64*32);
        load_lds16(gB,                lB);
        load_lds16(gB + (size_t)64*K, lB + 64*32);
        gA += 32; gB += 32;
        __syncthreads();
        bf16x8 af[4], bf[4];
        #pragma unroll
        for (int i = 0; i < 4; ++i) {
            af[i] = *(const bf16x8*)&As[(wm + i*16 + lr)*32 + quad*8];
            bf[i] = *(const bf16x8*)&Bs[(wn + i*16 + lr)*32 + quad*8];
        }
        #pragma unroll
        for (int mt = 0; mt < 4; ++mt)
            #pragma unroll
            for (int nt = 0; nt < 4; ++nt)
                acc[mt][nt] = __builtin_amdgcn_mfma_f32_16x16x32_bf16(af[mt], bf[nt], acc[mt][nt], 0, 0, 0);
    }

    #pragma unroll
    for (int nt = 0; nt < 4; ++nt) {
        int col = n0 + wn + nt*16 + lr;
        float bval;
        if constexpr (MODE == 5) {
            int seg = col >> 10, cs = col & 1023;
            bval = (seg == 0 ? bias : (seg == 1 ? bias2 : bias3))[cs];
        } else {
            bval = bias[col];
        }
        #pragma unroll
        for (int mt = 0; mt < 4; ++mt) {
            #pragma unroll
            for (int r = 0; r < 4; ++r) {
                int row = m0 + wm + mt*16 + quad*4 + r;
                float v = acc[mt][nt][r] + bval;
                if constexpr (MODE == 1) {
                    if constexpr (RESF) v += ((const float*)res)[(size_t)row*N + col];
                    else                v += b2f(((const u16*)res)[(size_t)row*N + col]);
                }
                if constexpr (MODE == 2) v = gelu_f(v);
                if constexpr (MODE == 5) {
                    int seg = col >> 10, cs = col & 1023;
                    int b = row >> 11, s = row & 2047, h = cs >> 6, d = cs & 63;
                    u16* dst = (u16*)(seg == 0 ? C : (seg == 1 ? C2 : C3));
                    dst[(((size_t)(b*NH + h)*S_LEN + s) << 6) + d] = f2b(v);
                } else {
                    size_t idx = (size_t)row*N + col;
                    if constexpr (OUTF) ((float*)C)[idx] = v;
                    else                ((u16*)C)[idx]   = f2b(v);
                }
            }
        }
    }
}

// ---------------------------------------------------------------- attention (causal)
// Grid (bh fastest, pair slowest): all blocks of a head land on one XCD (id%8 = bh%8)
// -> KV stays L2-local. Each block does the complementary pair {qt, 31-qt} -> uniform
// 33 tiles/block, zero causal tail. Waves split q (16 rows each); zero barriers.
// Register prefetch: V(kb) + K(kb+1) issued before softmax VALU to hide L2 latency.
// Q,K: [B*H][S][64]; Vt: [B*H][64][S]; O: [B][S][1024]
__global__ __launch_bounds__(256, 2)
void attn_kernel(const u16* __restrict__ Q, const u16* __restrict__ Kg,
                 const u16* __restrict__ Vt, u16* __restrict__ O)
{
    const int bh = blockIdx.x;            // fastest -> XCD = bh % 8
    const int pr = blockIdx.y;            // 0..15
    const int t = threadIdx.x, wave = t >> 6, lane = t & 63;
    const int lr = lane & 15, quad = lane >> 4;

    __shared__ __align__(16) u16 Ps[4][16*72];    // 9216 B

    const size_t qkbase = (size_t)bh * (S_LEN*HD);
    const int b = bh >> 4, h = bh & 15;
    u16* Pw = Ps[wave];
    const f32x4 fzero = {0.f, 0.f, 0.f, 0.f};

    #pragma unroll
    for (int half = 0; half < 2; ++half) {
        const int qt = half ? (31 - pr) : pr;
        const int qrow0 = qt*64 + wave*16;
        const int qrowq = qrow0 + quad*4;

        const u16* qp = Q + qkbase + (size_t)(qrow0 + lr)*HD + quad*8;
        bf16x8 qf0 = *(const bf16x8*)qp;
        bf16x8 qf1 = *(const bf16x8*)(qp + 32);

        f32x4 oacc[4];
        float lpart[4];
        #pragma unroll
        for (int dt = 0; dt < 4; ++dt) oacc[dt] = fzero;
        #pragma unroll
        for (int r = 0; r < 4; ++r) lpart[r] = 0.f;

        // preload K tile 0
        bf16x8 kc0[4], kc1[4];
        #pragma unroll
        for (int i = 0; i < 4; ++i) {
            const u16* kp = Kg + qkbase + (size_t)(i*16 + lr)*HD + quad*8;
            kc0[i] = *(const bf16x8*)kp;
            kc1[i] = *(const bf16x8*)(kp + 32);
        }

        for (int kb = 0; kb <= qt; ++kb) {
            // issue V(kb) loads early (consumed after softmax)
            bf16x8 vf0[4], vf1[4];
            #pragma unroll
            for (int dt = 0; dt < 4; ++dt) {
                const u16* vp = Vt + qkbase + (size_t)(dt*16 + lr)*S_LEN + kb*64 + quad*8;
                vf0[dt] = *(const bf16x8*)vp;
                vf1[dt] = *(const bf16x8*)(vp + 32);
            }
            // issue K(kb+1) prefetch (clamped; consumed next iteration)
            const int kbn = (kb < qt) ? kb + 1 : kb;
            bf16x8 kn0[4], kn1[4];
            #pragma unroll
            for (int i = 0; i < 4; ++i) {
                const u16* kp = Kg + qkbase + (size_t)(kbn*64 + i*16 + lr)*HD + quad*8;
                kn0[i] = *(const bf16x8*)kp;
                kn1[i] = *(const bf16x8*)(kp + 32);
            }

            // QK^T with current K fragments
            f32x4 sc[4];
            #pragma unroll
            for (int kt2 = 0; kt2 < 4; ++kt2) {
                sc[kt2] = __builtin_amdgcn_mfma_f32_16x16x32_bf16(qf0, kc0[kt2], fzero, 0, 0, 0);
                sc[kt2] = __builtin_amdgcn_mfma_f32_16x16x32_bf16(qf1, kc1[kt2], sc[kt2], 0, 0, 0);
            }
            const bool diag = (kb == qt);
            #pragma unroll
            for (int r = 0; r < 4; ++r) {
                #pragma unroll
                for (int kt2 = 0; kt2 < 4; ++kt2) {
                    int kcol = kb*64 + kt2*16 + lr;
                    float p = (!diag || kcol <= qrowq + r) ? __expf(fminf(sc[kt2][r]*0.125f, 30.f)) : 0.f;
                    lpart[r] += p;
                    Pw[(quad*4 + r)*72 + kt2*16 + lr] = f2b(p);
                }
            }
            // PV (P via wave-private LDS round-trip)
            bf16x8 pf0 = *(const bf16x8*)&Pw[lr*72 + quad*8];
            bf16x8 pf1 = *(const bf16x8*)&Pw[lr*72 + 32 + quad*8];
            #pragma unroll
            for (int dt = 0; dt < 4; ++dt) {
                oacc[dt] = __builtin_amdgcn_mfma_f32_16x16x32_bf16(pf0, vf0[dt], oacc[dt], 0, 0, 0);
                oacc[dt] = __builtin_amdgcn_mfma_f32_16x16x32_bf16(pf1, vf1[dt], oacc[dt], 0, 0, 0);
            }
            // rotate prefetched K
            #pragma unroll
            for (int i = 0; i < 4; ++i) { kc0[i] = kn0[i]; kc1[i] = kn1[i]; }
        }

        // fold lpart across the 16 lr lanes
        #pragma unroll
        for (int r = 0; r < 4; ++r) {
            float v = lpart[r];
            v += __shfl_xor(v, 1, 64); v += __shfl_xor(v, 2, 64);
            v += __shfl_xor(v, 4, 64); v += __shfl_xor(v, 8, 64);
            lpart[r] = 1.0f / fmaxf(v, 1e-20f);
        }

        // stage output tile (16x64 bf16) through dead P space, then 16B stores
        #pragma unroll
        for (int dt = 0; dt < 4; ++dt)
            #pragma unroll
            for (int r = 0; r < 4; ++r)
                Pw[(quad*4 + r)*64 + dt*16 + lr] = f2b(oacc[dt][r] * lpart[r]);

        const int q = lane >> 2, d0 = (lane & 3)*16;
        u16* dst = O + ((size_t)(b*S_LEN + qrow0 + q))*EMB + h*HD + d0;
        *(uint4*)(dst)     = *(uint4*)&Pw[q*64 + d0];
        *(uint4*)(dst + 8) = *(uint4*)&Pw[q*64 + d0 + 8];
    }
}

// ---------------------------------------------------------------- launch
extern "C" void kernel_launch(void* const* d_in, const int* in_sizes, int n_in,
                              void* d_out, int out_size, void* d_ws, size_t ws_size,
                              hipStream_t stream)
{
    (void)in_sizes; (void)n_in; (void)out_size; (void)ws_size;
    const float* x    = (const float*)d_in[0];
    // d_in[1] = mask: causal tril, handled analytically
    const float* ln1g = (const float*)d_in[2];
    const float* ln1b = (const float*)d_in[3];
    const float* wq = (const float*)d_in[4];  const float* bq = (const float*)d_in[5];
    const float* wk = (const float*)d_in[6];  const float* bk = (const float*)d_in[7];
    const float* wv = (const float*)d_in[8];  const float* bv = (const float*)d_in[9];
    const float* wo = (const float*)d_in[10]; const float* bo = (const float*)d_in[11];
    const float* ln2g = (const float*)d_in[12]; const float* ln2b = (const float*)d_in[13];
    const float* w1 = (const float*)d_in[14]; const float* b1 = (const float*)d_in[15];
    const float* w2 = (const float*)d_in[16]; const float* b2 = (const float*)d_in[17];

    u16* ws = (u16*)d_ws;
    const size_t M1 = 1u << 20;             // 1M u16 elements (2 MB)
    u16* wqkvT = ws + 0*M1;                 // bf16 [3072][1024] = wqT|wkT|wvT contiguous
    u16* wqT = ws + 0*M1;
    u16* wkT = ws + 1*M1;
    u16* wvT = ws + 2*M1;
    u16* woT = ws + 3*M1;
    u16* w2T = ws + 0*M1;                   // bf16 [1024][4096], transposed AFTER wo-gemm
    u16* w1T = ws + 4*M1;                   // bf16 [4096][1024]
    u16* h0  = ws + 8*M1;                   // bf16 ln out (reused for ln2 out)
    u16* qb  = ws + 12*M1;                  // bf16 [B,H,S,D]
    u16* kb  = ws + 16*M1;                  // bf16 [B,H,S,D]
    u16* vT  = ws + 20*M1;                  // bf16 [B,H,D,S]
    u16* ao  = ws + 24*M1;                  // bf16 attn out [B,S,E]
    u16* vb  = ws + 24*M1;                  // bf16 V [B,H,S,D] (dead before attn writes ao)
    u16* x1  = ws + 28*M1;                  // bf16 residual-1 out
    u16* fb  = ws + 12*M1;                  // bf16 MLP hidden, overlays q/k/v/ao (dead)

    dim3 blk(256);
    transpose_k<<<dim3(16,16), blk, 0, stream>>>(wq, wqT, EMB, EMB);
    transpose_k<<<dim3(16,16), blk, 0, stream>>>(wk, wkT, EMB, EMB);
    transpose_k<<<dim3(16,16), blk, 0, stream>>>(wv, wvT, EMB, EMB);
    transpose_k<<<dim3(16,16), blk, 0, stream>>>(wo, woT, EMB, EMB);
    transpose_k<<<dim3(64,16), blk, 0, stream>>>(w1, w1T, EMB, FF_DIM);

    ln_kernel<1><<<NROWS, blk, 0, stream>>>(x, ln1g, ln1b, h0);

    gemm_bt<5,0,0><<<dim3(24,32), blk, 0, stream>>>(h0, wqkvT, bq, bk, bv, nullptr,
                                                    qb, kb, vb, NROWS, 3072, EMB);

    vtrans<<<dim3(32,32), blk, 0, stream>>>(vb, vT);

    attn_kernel<<<dim3(32,16), blk, 0, stream>>>(qb, kb, vT, ao);

    gemm_bt<1,1,0><<<dim3(8,32),  blk, 0, stream>>>(ao, woT, bo, nullptr, nullptr, x,
                                                    x1, nullptr, nullptr, NROWS, EMB, EMB);

    transpose_k<<<dim3(16,64), blk, 0, stream>>>(w2, w2T, FF_DIM, EMB);

    ln_kernel<0><<<NROWS, blk, 0, stream>>>(x1, ln2g, ln2b, h0);

    gemm_bt<2,0,0><<<dim3(32,32), blk, 0, stream>>>(h0, w1T, b1, nullptr, nullptr, nullptr,
                                                    fb, nullptr, nullptr, NROWS, FF_DIM, EMB);
    gemm_bt<1,0,1><<<dim3(8,32),  blk, 0, stream>>>(fb, w2T, b2, nullptr, nullptr, x1,
                                                    d_out, nullptr, nullptr, NROWS, EMB, FF_DIM);
}

// Round 8
// 456.024 us; speedup vs baseline: 1.1692x; 1.1088x over previous
//
#include <hip/hip_runtime.h>

typedef unsigned short u16;
typedef unsigned int   u32;
typedef __attribute__((ext_vector_type(8))) short bf16x8;   // 8 bf16 in 4 VGPRs
typedef __attribute__((ext_vector_type(4))) float f32x4;

#define S_LEN 2048
#define EMB   1024
#define NH    16
#define HD    64
#define FF_DIM 4096
#define NROWS 4096   // B*S

__device__ __forceinline__ float b2f(u16 u){ union{u32 i; float f;} c; c.i = ((u32)u)<<16; return c.f; }
// round-half-up bf16 pack: 2 VALU ops (vs 5 for RNE); differs from RNE only on exact ties
__device__ __forceinline__ u16 f2b(float f){ union{float f; u32 u;} c; c.f=f; return (u16)((c.u + 0x8000u)>>16); }
__device__ __forceinline__ float gelu_f(float x){ return 0.5f*x*(1.0f + erff(x*0.70710678118f)); }

// async global->LDS, 16B per lane; lds dest = wave-uniform base + lane*16 (m97/m104)
__device__ __forceinline__ void load_lds16(const u16* g, u16* l) {
    __builtin_amdgcn_global_load_lds((const __attribute__((address_space(1))) u32*)g,
                                     (__attribute__((address_space(3))) u32*)l, 16, 0, 0);
}

// ---------------------------------------------------------------- LayerNorm
template<int XF32>
__global__ __launch_bounds__(256)
void ln_kernel(const void* __restrict__ Xv, const float* __restrict__ G,
               const float* __restrict__ Bv, u16* __restrict__ Y)
{
    const int row = blockIdx.x, t = threadIdx.x;
    float v0, v1, v2, v3;
    if constexpr (XF32) {
        float4 r4 = ((const float4*)((const float*)Xv + (size_t)row*EMB))[t];
        v0 = r4.x; v1 = r4.y; v2 = r4.z; v3 = r4.w;
    } else {
        const u16* xr = (const u16*)Xv + (size_t)row*EMB;
        uint2 raw = *(const uint2*)(xr + t*4);
        v0 = b2f(raw.x & 0xffff); v1 = b2f(raw.x >> 16);
        v2 = b2f(raw.y & 0xffff); v3 = b2f(raw.y >> 16);
    }
    float s  = v0+v1+v2+v3;
    float s2 = v0*v0+v1*v1+v2*v2+v3*v3;
    #pragma unroll
    for (int off = 1; off < 64; off <<= 1) {
        s  += __shfl_xor(s,  off, 64);
        s2 += __shfl_xor(s2, off, 64);
    }
    __shared__ float ps[4], ps2[4];
    const int w = t >> 6, lane = t & 63;
    if (lane == 0) { ps[w] = s; ps2[w] = s2; }
    __syncthreads();
    s  = ps[0]+ps[1]+ps[2]+ps[3];
    s2 = ps2[0]+ps2[1]+ps2[2]+ps2[3];
    const float mu   = s * (1.0f/EMB);
    const float rstd = rsqrtf(fmaxf(s2*(1.0f/EMB) - mu*mu, 0.f) + 1e-5f);
    float4 g4 = ((const float4*)G)[t];
    float4 c4 = ((const float4*)Bv)[t];
    u32 lo = (u32)f2b((v0-mu)*rstd*g4.x + c4.x) | ((u32)f2b((v1-mu)*rstd*g4.y + c4.y) << 16);
    u32 hi = (u32)f2b((v2-mu)*rstd*g4.z + c4.z) | ((u32)f2b((v3-mu)*rstd*g4.w + c4.w) << 16);
    uint2 o; o.x = lo; o.y = hi;
    *(uint2*)(Y + (size_t)row*EMB + t*4) = o;
}

// ---------------------------------------------------------------- transpose+downconvert (f32 [K][N] -> bf16 [N][K])
__global__ __launch_bounds__(256)
void transpose_k(const float* __restrict__ in, u16* __restrict__ out, int K, int N)
{
    __shared__ __align__(16) u16 T[64*72];
    const int k0 = blockIdx.y*64, n0 = blockIdx.x*64, t = threadIdx.x;
    #pragma unroll
    for (int c = 0; c < 4; ++c) {
        int e = t*4 + c*1024, ki = e >> 6, nj = e & 63;
        float4 f = *(const float4*)(in + (size_t)(k0+ki)*N + n0 + nj);
        ushort4 s4; s4.x = f2b(f.x); s4.y = f2b(f.y); s4.z = f2b(f.z); s4.w = f2b(f.w);
        *(ushort4*)&T[ki*72 + nj] = s4;
    }
    __syncthreads();
    #pragma unroll
    for (int c = 0; c < 2; ++c) {
        int e = t*8 + c*2048, ni = e >> 6, kj = e & 63;
        uint4 v; u16* pv = (u16*)&v;
        #pragma unroll
        for (int j = 0; j < 8; ++j) pv[j] = T[(kj+j)*72 + ni];
        *(uint4*)(out + (size_t)(n0+ni)*K + k0 + kj) = v;
    }
}

// ---------------------------------------------------------------- bf16 transpose: V [B*H][S][64] -> V^T [B*H][64][S]
__global__ __launch_bounds__(256)
void vtrans(const u16* __restrict__ in, u16* __restrict__ out)
{
    __shared__ __align__(16) u16 T[64*72];
    const int bh = blockIdx.y, s0 = blockIdx.x*64, t = threadIdx.x;
    const size_t base = (size_t)bh * (S_LEN*HD);
    #pragma unroll
    for (int c = 0; c < 2; ++c) {
        int e = t*8 + c*2048, r = e >> 6, d = e & 63;
        *(uint4*)&T[r*72 + d] = *(const uint4*)(in + base + (size_t)(s0 + r)*HD + d);
    }
    __syncthreads();
    #pragma unroll
    for (int c = 0; c < 2; ++c) {
        int e = t*8 + c*2048, d = e >> 6, sj = e & 63;
        uint4 v; u16* pv = (u16*)&v;
        #pragma unroll
        for (int j = 0; j < 8; ++j) pv[j] = T[(sj + j)*72 + d];
        *(uint4*)(out + base + (size_t)d*S_LEN + s0 + sj) = v;
    }
}

// ---------------------------------------------------------------- GEMM: C = A @ Bt^T + bias
// m97-style global_load_lds staging + LDS-staged coalesced epilogue (dwordx4 row stores).
// MODE 0: plain  1: +res  2: gelu  5: fused QKV (C=Q,C2=K,C3=V, all head-split [B,H,S,D])
// RESF: res f32(1)/bf16(0).  OUTF: C f32(1)/bf16(0).
template<int MODE, int RESF, int OUTF>
__global__ __launch_bounds__(256)
void gemm_bt(const u16* __restrict__ A, const u16* __restrict__ Bt,
             const float* __restrict__ bias, const float* __restrict__ bias2,
             const float* __restrict__ bias3, const void* __restrict__ res,
             void* __restrict__ C, void* __restrict__ C2, void* __restrict__ C3,
             int M, int N, int K)
{
    __shared__ __align__(16) u16 Sm[8704];      // K-loop: As=Sm[0..4095], Bs=Sm[4096..8191]; epilogue: 64x136
    u16* As = Sm;
    u16* Bs = Sm + 4096;
    const int t = threadIdx.x;
    const int m0 = blockIdx.y*128, n0 = blockIdx.x*128;
    const int wave = t >> 6, lane = t & 63;
    const int wm = (wave >> 1)*64, wn = (wave & 1)*64;
    const int lr = lane & 15, quad = lane >> 4;

    const int srow = wave*16 + (lane >> 2);
    const int scol = (lane & 3)*8;
    const u16* gA = A  + (size_t)(m0 + srow)*K + scol;
    const u16* gB = Bt + (size_t)(n0 + srow)*K + scol;
    u16* lA = &As[wave*16*32];
    u16* lB = &Bs[wave*16*32];

    f32x4 acc[4][4];
    const f32x4 fzero = {0.f, 0.f, 0.f, 0.f};
    #pragma unroll
    for (int mt = 0; mt < 4; ++mt)
        #pragma unroll
        for (int nt = 0; nt < 4; ++nt) acc[mt][nt] = fzero;

    for (int kt = 0; kt < K; kt += 32) {
        __syncthreads();
        load_lds16(gA,                lA);
        load_lds16(gA + (size_t)64*K, lA + 64*32);
        load_lds16(gB,                lB);
        load_lds16(gB + (size_t)64*K, lB + 64*32);
        gA += 32; gB += 32;
        __syncthreads();
        bf16x8 af[4], bf[4];
        #pragma unroll
        for (int i = 0; i < 4; ++i) {
            af[i] = *(const bf16x8*)&As[(wm + i*16 + lr)*32 + quad*8];
            bf[i] = *(const bf16x8*)&Bs[(wn + i*16 + lr)*32 + quad*8];
        }
        #pragma unroll
        for (int mt = 0; mt < 4; ++mt)
            #pragma unroll
            for (int nt = 0; nt < 4; ++nt)
                acc[mt][nt] = __builtin_amdgcn_mfma_f32_16x16x32_bf16(af[mt], bf[nt], acc[mt][nt], 0, 0, 0);
    }

    // ---------------- epilogue: stage 64-row chunks in LDS, store coalesced rows
    // MODE 5: whole 128-col tile lies in one segment (1024 % 128 == 0)
    u16* qkvDst = nullptr;
    if constexpr (MODE == 5) {
        int seg = n0 >> 10;
        qkvDst = (u16*)(seg == 0 ? C : (seg == 1 ? C2 : C3));
    }

    #pragma unroll
    for (int c = 0; c < 2; ++c) {
        __syncthreads();                      // previous LDS use complete
        if ((wave >> 1) == c) {
            #pragma unroll
            for (int nt = 0; nt < 4; ++nt) {
                int colL = wn + nt*16 + lr;
                float bval;
                if constexpr (MODE == 5) {
                    int col = n0 + colL;
                    int seg = col >> 10, cs = col & 1023;
                    bval = (seg == 0 ? bias : (seg == 1 ? bias2 : bias3))[cs];
                } else {
                    bval = bias[n0 + colL];
                }
                #pragma unroll
                for (int mt = 0; mt < 4; ++mt) {
                    #pragma unroll
                    for (int r = 0; r < 4; ++r) {
                        int rowL = mt*16 + quad*4 + r;        // 0..63 within chunk
                        float v = acc[mt][nt][r] + bval;
                        if constexpr (MODE == 2) v = gelu_f(v);
                        Sm[rowL*136 + colL] = f2b(v);
                    }
                }
            }
        }
        __syncthreads();
        // cooperative store: 64 rows x 128 cols, 16 B/lane
        #pragma unroll
        for (int i = 0; i < 4; ++i) {
            const int rowL = wave*16 + i*4 + (lane >> 4);
            const int colL = (lane & 15)*8;
            const int row  = m0 + c*64 + rowL;
            const u16* src = &Sm[rowL*136 + colL];
            if constexpr (MODE == 5) {
                int cs = (n0 + colL) & 1023;
                int h = cs >> 6, d = cs & 63;
                int b_ = row >> 11, s = row & 2047;
                u16* dst = qkvDst + ((((size_t)(b_*NH + h))*S_LEN + s) << 6) + d;
                *(uint4*)dst = *(const uint4*)src;
            } else {
                size_t base = (size_t)row*N + n0 + colL;
                if constexpr (MODE == 1 || OUTF) {
                    uint4 sv = *(const uint4*)src;
                    const u16* sp = (const u16*)&sv;
                    float f[8];
                    #pragma unroll
                    for (int j = 0; j < 8; ++j) f[j] = b2f(sp[j]);
                    if constexpr (MODE == 1) {
                        if constexpr (RESF) {
                            const float* rp = (const float*)res + base;
                            float4 r0 = *(const float4*)rp, r1 = *(const float4*)(rp+4);
                            f[0]+=r0.x; f[1]+=r0.y; f[2]+=r0.z; f[3]+=r0.w;
                            f[4]+=r1.x; f[5]+=r1.y; f[6]+=r1.z; f[7]+=r1.w;
                        } else {
                            uint4 rv = *(const uint4*)((const u16*)res + base);
                            const u16* rp = (const u16*)&rv;
                            #pragma unroll
                            for (int j = 0; j < 8; ++j) f[j] += b2f(rp[j]);
                        }
                    }
                    if constexpr (OUTF) {
                        float* op = (float*)C + base;
                        float4 o0 = {f[0],f[1],f[2],f[3]}, o1 = {f[4],f[5],f[6],f[7]};
                        *(float4*)op = o0; *(float4*)(op+4) = o1;
                    } else {
                        u16 ov[8];
                        #pragma unroll
                        for (int j = 0; j < 8; ++j) ov[j] = f2b(f[j]);
                        *(uint4*)((u16*)C + base) = *(const uint4*)ov;
                    }
                } else {
                    *(uint4*)((u16*)C + base) = *(const uint4*)src;
                }
            }
        }
    }
}

// ---------------------------------------------------------------- attention (causal)
// Grid (bh fastest): XCD-local KV. Block handles pair {pr, 31-pr}; ONE merged K-loop
// stages each K/V tile once via global_load_lds (shared by 4 waves) and feeds up to
// two Q-tiles. LDS layout [k-half][row][32] keeps the m97 64-B-stride fragment reads.
// Q,K: [B*H][S][64]; Vt: [B*H][64][S]; O: [B][S][1024]
__global__ __launch_bounds__(256, 2)
void attn_kernel(const u16* __restrict__ Q, const u16* __restrict__ Kg,
                 const u16* __restrict__ Vt, u16* __restrict__ O)
{
    const int bh = blockIdx.x;            // fastest -> XCD = bh % 8
    const int pr = blockIdx.y;            // 0..15
    const int qta = pr, qtb = 31 - pr;
    const int t = threadIdx.x, wave = t >> 6, lane = t & 63;
    const int lr = lane & 15, quad = lane >> 4;

    __shared__ __align__(16) u16 Ks[4096];        // [2][64][32]
    __shared__ __align__(16) u16 Vs[4096];        // [2][64][32]
    __shared__ __align__(16) u16 Ps[4][16*72];    // wave-private P round-trip

    const size_t qkbase = (size_t)bh * (S_LEN*HD);
    const int b = bh >> 4, h = bh & 15;
    u16* Pw = Ps[wave];
    const f32x4 fzero = {0.f, 0.f, 0.f, 0.f};

    // Q fragments for both tiles (wave owns 16 q rows per tile)
    const u16* qpa = Q + qkbase + (size_t)(qta*64 + wave*16 + lr)*HD + quad*8;
    const u16* qpb = Q + qkbase + (size_t)(qtb*64 + wave*16 + lr)*HD + quad*8;
    bf16x8 qa0 = *(const bf16x8*)qpa, qa1 = *(const bf16x8*)(qpa + 32);
    bf16x8 qb0 = *(const bf16x8*)qpb, qb1 = *(const bf16x8*)(qpb + 32);

    f32x4 oa[4], ob[4];
    float la[4], lb[4];
    #pragma unroll
    for (int dt = 0; dt < 4; ++dt) { oa[dt] = fzero; ob[dt] = fzero; }
    #pragma unroll
    for (int r = 0; r < 4; ++r) { la[r] = 0.f; lb[r] = 0.f; }

    // staging addresses (per wave: 16 rows of each half)
    const u16* gK = Kg + qkbase + (size_t)(wave*16 + (lane>>2))*HD + (lane&3)*8;
    const u16* gV = Vt + qkbase + (size_t)(wave*16 + (lane>>2))*S_LEN + (lane&3)*8;
    u16* lK = Ks + wave*512;
    u16* lV = Vs + wave*512;

    const int qrow_qa = qta*64 + wave*16 + quad*4;
    const int qrow_qb = qtb*64 + wave*16 + quad*4;

    for (int kb = 0; kb <= qtb; ++kb) {
        __syncthreads();                           // prior compute done reading Ks/Vs
        load_lds16(gK + (size_t)kb*4096,      lK);
        load_lds16(gK + (size_t)kb*4096 + 32, lK + 2048);
        load_lds16(gV + kb*64,                lV);
        load_lds16(gV + kb*64 + 32,           lV + 2048);
        __syncthreads();                           // staging complete (vmcnt drained)

        #pragma unroll
        for (int tile = 0; tile < 2; ++tile) {
            const int qt = tile ? qta : qtb;
            if (tile && kb > qta) break;
            bf16x8 qf0 = tile ? qa0 : qb0;
            bf16x8 qf1 = tile ? qa1 : qb1;
            f32x4* oacc = tile ? oa : ob;
            float* lp   = tile ? la : lb;
            const int qrowq = tile ? qrow_qa : qrow_qb;

            f32x4 sc[4];
            #pragma unroll
            for (int kt2 = 0; kt2 < 4; ++kt2) {
                bf16x8 kf0 = *(const bf16x8*)&Ks[(kt2*16 + lr)*32 + quad*8];
                bf16x8 kf1 = *(const bf16x8*)&Ks[2048 + (kt2*16 + lr)*32 + quad*8];
                sc[kt2] = __builtin_amdgcn_mfma_f32_16x16x32_bf16(qf0, kf0, fzero, 0, 0, 0);
                sc[kt2] = __builtin_amdgcn_mfma_f32_16x16x32_bf16(qf1, kf1, sc[kt2], 0, 0, 0);
            }
            const bool diag = (kb == qt);
            #pragma unroll
            for (int r = 0; r < 4; ++r) {
                #pragma unroll
                for (int kt2 = 0; kt2 < 4; ++kt2) {
                    int kcol = kb*64 + kt2*16 + lr;
                    float p = (!diag || kcol <= qrowq + r) ? __expf(fminf(sc[kt2][r]*0.125f, 30.f)) : 0.f;
                    lp[r] += p;
                    Pw[(quad*4 + r)*72 + kt2*16 + lr] = f2b(p);
                }
            }
            bf16x8 pf0 = *(const bf16x8*)&Pw[lr*72 + quad*8];
            bf16x8 pf1 = *(const bf16x8*)&Pw[lr*72 + 32 + quad*8];
            #pragma unroll
            for (int dt = 0; dt < 4; ++dt) {
                bf16x8 vf0 = *(const bf16x8*)&Vs[(dt*16 + lr)*32 + quad*8];
                bf16x8 vf1 = *(const bf16x8*)&Vs[2048 + (dt*16 + lr)*32 + quad*8];
                oacc[dt] = __builtin_amdgcn_mfma_f32_16x16x32_bf16(pf0, vf0, oacc[dt], 0, 0, 0);
                oacc[dt] = __builtin_amdgcn_mfma_f32_16x16x32_bf16(pf1, vf1, oacc[dt], 0, 0, 0);
            }
        }
    }

    // finalize both tiles: fold l across 16 lr lanes, scale, write via P-space staging
    #pragma unroll
    for (int tile = 0; tile < 2; ++tile) {
        const int qt = tile ? qta : qtb;
        f32x4* oacc = tile ? oa : ob;
        float* lp   = tile ? la : lb;
        #pragma unroll
        for (int r = 0; r < 4; ++r) {
            float v = lp[r];
            v += __shfl_xor(v, 1, 64); v += __shfl_xor(v, 2, 64);
            v += __shfl_xor(v, 4, 64); v += __shfl_xor(v, 8, 64);
            lp[r] = 1.0f / fmaxf(v, 1e-20f);
        }
        #pragma unroll
        for (int dt = 0; dt < 4; ++dt)
            #pragma unroll
            for (int r = 0; r < 4; ++r)
                Pw[(quad*4 + r)*64 + dt*16 + lr] = f2b(oacc[dt][r] * lp[r]);

        const int q = lane >> 2, d0 = (lane & 3)*16;
        u16* dst = O + ((size_t)(b*S_LEN + qt*64 + wave*16 + q))*EMB + h*HD + d0;
        *(uint4*)(dst)     = *(uint4*)&Pw[q*64 + d0];
        *(uint4*)(dst + 8) = *(uint4*)&Pw[q*64 + d0 + 8];
    }
}

// ---------------------------------------------------------------- launch
extern "C" void kernel_launch(void* const* d_in, const int* in_sizes, int n_in,
                              void* d_out, int out_size, void* d_ws, size_t ws_size,
                              hipStream_t stream)
{
    (void)in_sizes; (void)n_in; (void)out_size; (void)ws_size;
    const float* x    = (const float*)d_in[0];
    // d_in[1] = mask: causal tril, handled analytically
    const float* ln1g = (const float*)d_in[2];
    const float* ln1b = (const float*)d_in[3];
    const float* wq = (const float*)d_in[4];  const float* bq = (const float*)d_in[5];
    const float* wk = (const float*)d_in[6];  const float* bk = (const float*)d_in[7];
    const float* wv = (const float*)d_in[8];  const float* bv = (const float*)d_in[9];
    const float* wo = (const float*)d_in[10]; const float* bo = (const float*)d_in[11];
    const float* ln2g = (const float*)d_in[12]; const float* ln2b = (const float*)d_in[13];
    const float* w1 = (const float*)d_in[14]; const float* b1 = (const float*)d_in[15];
    const float* w2 = (const float*)d_in[16]; const float* b2 = (const float*)d_in[17];

    u16* ws = (u16*)d_ws;
    const size_t M1 = 1u << 20;             // 1M u16 elements (2 MB)
    u16* wqkvT = ws + 0*M1;                 // bf16 [3072][1024] = wqT|wkT|wvT contiguous
    u16* wqT = ws + 0*M1;
    u16* wkT = ws + 1*M1;
    u16* wvT = ws + 2*M1;
    u16* woT = ws + 3*M1;
    u16* w2T = ws + 0*M1;                   // bf16 [1024][4096], transposed AFTER wo-gemm
    u16* w1T = ws + 4*M1;                   // bf16 [4096][1024]
    u16* h0  = ws + 8*M1;                   // bf16 ln out (reused for ln2 out)
    u16* qb  = ws + 12*M1;                  // bf16 [B,H,S,D]
    u16* kb  = ws + 16*M1;                  // bf16 [B,H,S,D]
    u16* vT  = ws + 20*M1;                  // bf16 [B,H,D,S]
    u16* ao  = ws + 24*M1;                  // bf16 attn out [B,S,E]
    u16* vb  = ws + 24*M1;                  // bf16 V [B,H,S,D] (dead before attn writes ao)
    u16* x1  = ws + 28*M1;                  // bf16 residual-1 out
    u16* fb  = ws + 12*M1;                  // bf16 MLP hidden, overlays q/k/v/ao (dead)

    dim3 blk(256);
    transpose_k<<<dim3(16,16), blk, 0, stream>>>(wq, wqT, EMB, EMB);
    transpose_k<<<dim3(16,16), blk, 0, stream>>>(wk, wkT, EMB, EMB);
    transpose_k<<<dim3(16,16), blk, 0, stream>>>(wv, wvT, EMB, EMB);
    transpose_k<<<dim3(16,16), blk, 0, stream>>>(wo, woT, EMB, EMB);
    transpose_k<<<dim3(64,16), blk, 0, stream>>>(w1, w1T, EMB, FF_DIM);

    ln_kernel<1><<<NROWS, blk, 0, stream>>>(x, ln1g, ln1b, h0);

    gemm_bt<5,0,0><<<dim3(24,32), blk, 0, stream>>>(h0, wqkvT, bq, bk, bv, nullptr,
                                                    qb, kb, vb, NROWS, 3072, EMB);

    vtrans<<<dim3(32,32), blk, 0, stream>>>(vb, vT);

    attn_kernel<<<dim3(32,16), blk, 0, stream>>>(qb, kb, vT, ao);

    gemm_bt<1,1,0><<<dim3(8,32),  blk, 0, stream>>>(ao, woT, bo, nullptr, nullptr, x,
                                                    x1, nullptr, nullptr, NROWS, EMB, EMB);

    transpose_k<<<dim3(16,64), blk, 0, stream>>>(w2, w2T, FF_DIM, EMB);

    ln_kernel<0><<<NROWS, blk, 0, stream>>>(x1, ln2g, ln2b, h0);

    gemm_bt<2,0,0><<<dim3(32,32), blk, 0, stream>>>(h0, w1T, b1, nullptr, nullptr, nullptr,
                                                    fb, nullptr, nullptr, NROWS, FF_DIM, EMB);
    gemm_bt<1,0,1><<<dim3(8,32),  blk, 0, stream>>>(fb, w2T, b2, nullptr, nullptr, x1,
                                                    d_out, nullptr, nullptr, NROWS, EMB, FF_DIM);
}

// Round 9
// 417.843 us; speedup vs baseline: 1.2760x; 1.0914x over previous
//
#include <hip/hip_runtime.h>

typedef unsigned short u16;
typedef unsigned int   u32;
typedef __attribute__((ext_vector_type(8))) short bf16x8;   // 8 bf16 in 4 VGPRs
typedef __attribute__((ext_vector_type(4))) float f32x4;

#define S_LEN 2048
#define EMB   1024
#define NH    16
#define HD    64
#define FF_DIM 4096
#define NROWS 4096   // B*S

__device__ __forceinline__ float b2f(u16 u){ union{u32 i; float f;} c; c.i = ((u32)u)<<16; return c.f; }
// round-half-up bf16 pack: 2 VALU ops (vs 5 for RNE); differs from RNE only on exact ties
__device__ __forceinline__ u16 f2b(float f){ union{float f; u32 u;} c; c.f=f; return (u16)((c.u + 0x8000u)>>16); }
__device__ __forceinline__ float gelu_f(float x){ return 0.5f*x*(1.0f + erff(x*0.70710678118f)); }

// async global->LDS, 16B per lane; lds dest = wave-uniform base + lane*16 (m97/m104)
__device__ __forceinline__ void load_lds16(const u16* g, u16* l) {
    __builtin_amdgcn_global_load_lds((const __attribute__((address_space(1))) u32*)g,
                                     (__attribute__((address_space(3))) u32*)l, 16, 0, 0);
}

// ---------------------------------------------------------------- LayerNorm
template<int XF32>
__global__ __launch_bounds__(256)
void ln_kernel(const void* __restrict__ Xv, const float* __restrict__ G,
               const float* __restrict__ Bv, u16* __restrict__ Y)
{
    const int row = blockIdx.x, t = threadIdx.x;
    float v0, v1, v2, v3;
    if constexpr (XF32) {
        float4 r4 = ((const float4*)((const float*)Xv + (size_t)row*EMB))[t];
        v0 = r4.x; v1 = r4.y; v2 = r4.z; v3 = r4.w;
    } else {
        const u16* xr = (const u16*)Xv + (size_t)row*EMB;
        uint2 raw = *(const uint2*)(xr + t*4);
        v0 = b2f(raw.x & 0xffff); v1 = b2f(raw.x >> 16);
        v2 = b2f(raw.y & 0xffff); v3 = b2f(raw.y >> 16);
    }
    float s  = v0+v1+v2+v3;
    float s2 = v0*v0+v1*v1+v2*v2+v3*v3;
    #pragma unroll
    for (int off = 1; off < 64; off <<= 1) {
        s  += __shfl_xor(s,  off, 64);
        s2 += __shfl_xor(s2, off, 64);
    }
    __shared__ float ps[4], ps2[4];
    const int w = t >> 6, lane = t & 63;
    if (lane == 0) { ps[w] = s; ps2[w] = s2; }
    __syncthreads();
    s  = ps[0]+ps[1]+ps[2]+ps[3];
    s2 = ps2[0]+ps2[1]+ps2[2]+ps2[3];
    const float mu   = s * (1.0f/EMB);
    const float rstd = rsqrtf(fmaxf(s2*(1.0f/EMB) - mu*mu, 0.f) + 1e-5f);
    float4 g4 = ((const float4*)G)[t];
    float4 c4 = ((const float4*)Bv)[t];
    u32 lo = (u32)f2b((v0-mu)*rstd*g4.x + c4.x) | ((u32)f2b((v1-mu)*rstd*g4.y + c4.y) << 16);
    u32 hi = (u32)f2b((v2-mu)*rstd*g4.z + c4.z) | ((u32)f2b((v3-mu)*rstd*g4.w + c4.w) << 16);
    uint2 o; o.x = lo; o.y = hi;
    *(uint2*)(Y + (size_t)row*EMB + t*4) = o;
}

// ---------------------------------------------------------------- transpose+downconvert (f32 [K][N] -> bf16 [N][K])
__global__ __launch_bounds__(256)
void transpose_k(const float* __restrict__ in, u16* __restrict__ out, int K, int N)
{
    __shared__ __align__(16) u16 T[64*72];
    const int k0 = blockIdx.y*64, n0 = blockIdx.x*64, t = threadIdx.x;
    #pragma unroll
    for (int c = 0; c < 4; ++c) {
        int e = t*4 + c*1024, ki = e >> 6, nj = e & 63;
        float4 f = *(const float4*)(in + (size_t)(k0+ki)*N + n0 + nj);
        ushort4 s4; s4.x = f2b(f.x); s4.y = f2b(f.y); s4.z = f2b(f.z); s4.w = f2b(f.w);
        *(ushort4*)&T[ki*72 + nj] = s4;
    }
    __syncthreads();
    #pragma unroll
    for (int c = 0; c < 2; ++c) {
        int e = t*8 + c*2048, ni = e >> 6, kj = e & 63;
        uint4 v; u16* pv = (u16*)&v;
        #pragma unroll
        for (int j = 0; j < 8; ++j) pv[j] = T[(kj+j)*72 + ni];
        *(uint4*)(out + (size_t)(n0+ni)*K + k0 + kj) = v;
    }
}

// ---------------------------------------------------------------- bf16 transpose: V [B*H][S][64] -> V^T [B*H][64][S]
__global__ __launch_bounds__(256)
void vtrans(const u16* __restrict__ in, u16* __restrict__ out)
{
    __shared__ __align__(16) u16 T[64*72];
    const int bh = blockIdx.y, s0 = blockIdx.x*64, t = threadIdx.x;
    const size_t base = (size_t)bh * (S_LEN*HD);
    #pragma unroll
    for (int c = 0; c < 2; ++c) {
        int e = t*8 + c*2048, r = e >> 6, d = e & 63;
        *(uint4*)&T[r*72 + d] = *(const uint4*)(in + base + (size_t)(s0 + r)*HD + d);
    }
    __syncthreads();
    #pragma unroll
    for (int c = 0; c < 2; ++c) {
        int e = t*8 + c*2048, d = e >> 6, sj = e & 63;
        uint4 v; u16* pv = (u16*)&v;
        #pragma unroll
        for (int j = 0; j < 8; ++j) pv[j] = T[(sj + j)*72 + d];
        *(uint4*)(out + base + (size_t)d*S_LEN + s0 + sj) = v;
    }
}

// ---------------------------------------------------------------- GEMM: C = A @ Bt^T + bias
// global_load_lds staging, BK=64 (two 32-col k-chunks per barrier), LDS-staged coalesced epilogue.
// TM: 128 (wave grid 2x2 of 64x64) or 64 (wave grid 2x2 of 32x64; grid-x = M-tiles for XCD A-locality).
// MODE 0: plain  1: +res  2: gelu  5: fused QKV (C=Q,C2=K,C3=V, head-split [B,H,S,D])
// RESF: res f32(1)/bf16(0).  OUTF: C f32(1)/bf16(0).
template<int MODE, int RESF, int OUTF, int TM>
__global__ __launch_bounds__(256)
void gemm_bt(const u16* __restrict__ A, const u16* __restrict__ Bt,
             const float* __restrict__ bias, const float* __restrict__ bias2,
             const float* __restrict__ bias3, const void* __restrict__ res,
             void* __restrict__ C, void* __restrict__ C2, void* __restrict__ C3,
             int M, int N, int K)
{
    constexpr int MT  = (TM == 128) ? 4 : 2;        // 16-row m-tiles per wave
    constexpr int ACH = TM * 32;                    // u16 per A k-chunk
    __shared__ __align__(16) u16 Sm[(TM == 128) ? 16384 : 12288];
    u16* As = Sm;
    u16* Bs = Sm + 2*ACH;
    const int t = threadIdx.x;
    const int m0 = (TM == 128) ? blockIdx.y*128 : blockIdx.x*64;
    const int n0 = (TM == 128) ? blockIdx.x*128 : blockIdx.y*128;
    const int wave = t >> 6, lane = t & 63;
    const int wm = (wave >> 1) * (TM/2);
    const int wn = (wave & 1) * 64;
    const int lr = lane & 15, quad = lane >> 4;

    const u16* gA = A  + (size_t)(m0 + wave*16 + (lane >> 2))*K + (lane & 3)*8;
    const u16* gB = Bt + (size_t)(n0 + wave*16 + (lane >> 2))*K + (lane & 3)*8;
    u16* lA = As + wave*512;
    u16* lB = Bs + wave*512;

    f32x4 acc[MT][4];
    const f32x4 fzero = {0.f, 0.f, 0.f, 0.f};
    #pragma unroll
    for (int mt = 0; mt < MT; ++mt)
        #pragma unroll
        for (int nt = 0; nt < 4; ++nt) acc[mt][nt] = fzero;

    for (int kt = 0; kt < K; kt += 64) {
        __syncthreads();
        #pragma unroll
        for (int c = 0; c < 2; ++c) {
            load_lds16(gA + c*32, lA + c*ACH);
            if constexpr (TM == 128)
                load_lds16(gA + (size_t)64*K + c*32, lA + c*ACH + 2048);
            load_lds16(gB + c*32, lB + c*4096);
            load_lds16(gB + (size_t)64*K + c*32, lB + c*4096 + 2048);
        }
        gA += 64; gB += 64;
        __syncthreads();
        #pragma unroll
        for (int ks = 0; ks < 2; ++ks) {
            bf16x8 af[MT], bf[4];
            #pragma unroll
            for (int i = 0; i < MT; ++i)
                af[i] = *(const bf16x8*)&As[ks*ACH + (wm + i*16 + lr)*32 + quad*8];
            #pragma unroll
            for (int i = 0; i < 4; ++i)
                bf[i] = *(const bf16x8*)&Bs[ks*4096 + (wn + i*16 + lr)*32 + quad*8];
            #pragma unroll
            for (int mt = 0; mt < MT; ++mt)
                #pragma unroll
                for (int nt = 0; nt < 4; ++nt)
                    acc[mt][nt] = __builtin_amdgcn_mfma_f32_16x16x32_bf16(af[mt], bf[nt], acc[mt][nt], 0, 0, 0);
        }
    }

    // ---------------- epilogue: stage rows in LDS, store coalesced 16 B/lane rows
    u16* qkvDst = nullptr;
    if constexpr (MODE == 5) {
        int seg = n0 >> 10;
        qkvDst = (u16*)(seg == 0 ? C : (seg == 1 ? C2 : C3));
    }

    #pragma unroll
    for (int c = 0; c < (TM == 128 ? 2 : 1); ++c) {
        __syncthreads();
        if (TM == 64 || (wave >> 1) == c) {
            #pragma unroll
            for (int nt = 0; nt < 4; ++nt) {
                int colL = wn + nt*16 + lr;
                float bval;
                if constexpr (MODE == 5) {
                    int col = n0 + colL;
                    int seg = col >> 10, cs = col & 1023;
                    bval = (seg == 0 ? bias : (seg == 1 ? bias2 : bias3))[cs];
                } else {
                    bval = bias[n0 + colL];
                }
                #pragma unroll
                for (int mt = 0; mt < MT; ++mt) {
                    #pragma unroll
                    for (int r = 0; r < 4; ++r) {
                        int rowL = (TM == 128 ? mt*16 : wm + mt*16) + quad*4 + r;   // 0..63
                        float v = acc[mt][nt][r] + bval;
                        if constexpr (MODE == 2) v = gelu_f(v);
                        Sm[rowL*136 + colL] = f2b(v);
                    }
                }
            }
        }
        __syncthreads();
        #pragma unroll
        for (int i = 0; i < 4; ++i) {
            const int rowL = wave*16 + i*4 + (lane >> 4);
            const int colL = (lane & 15)*8;
            const int row  = m0 + c*64 + rowL;
            const u16* src = &Sm[rowL*136 + colL];
            if constexpr (MODE == 5) {
                int cs = (n0 + colL) & 1023;
                int h = cs >> 6, d = cs & 63;
                int b_ = row >> 11, s = row & 2047;
                u16* dst = qkvDst + ((((size_t)(b_*NH + h))*S_LEN + s) << 6) + d;
                *(uint4*)dst = *(const uint4*)src;
            } else {
                size_t base = (size_t)row*N + n0 + colL;
                if constexpr (MODE == 1 || OUTF) {
                    uint4 sv = *(const uint4*)src;
                    const u16* sp = (const u16*)&sv;
                    float f[8];
                    #pragma unroll
                    for (int j = 0; j < 8; ++j) f[j] = b2f(sp[j]);
                    if constexpr (MODE == 1) {
                        if constexpr (RESF) {
                            const float* rp = (const float*)res + base;
                            float4 r0 = *(const float4*)rp, r1 = *(const float4*)(rp+4);
                            f[0]+=r0.x; f[1]+=r0.y; f[2]+=r0.z; f[3]+=r0.w;
                            f[4]+=r1.x; f[5]+=r1.y; f[6]+=r1.z; f[7]+=r1.w;
                        } else {
                            uint4 rv = *(const uint4*)((const u16*)res + base);
                            const u16* rp = (const u16*)&rv;
                            #pragma unroll
                            for (int j = 0; j < 8; ++j) f[j] += b2f(rp[j]);
                        }
                    }
                    if constexpr (OUTF) {
                        float* op = (float*)C + base;
                        float4 o0 = {f[0],f[1],f[2],f[3]}, o1 = {f[4],f[5],f[6],f[7]};
                        *(float4*)op = o0; *(float4*)(op+4) = o1;
                    } else {
                        u16 ov[8];
                        #pragma unroll
                        for (int j = 0; j < 8; ++j) ov[j] = f2b(f[j]);
                        *(uint4*)((u16*)C + base) = *(const uint4*)ov;
                    }
                } else {
                    *(uint4*)((u16*)C + base) = *(const uint4*)src;
                }
            }
        }
    }
}

// ---------------------------------------------------------------- attention (causal)
// Grid (bh fastest): XCD-local KV. Block handles pair {pr, 31-pr}; ONE merged K-loop
// stages each K/V tile once via global_load_lds (shared by 4 waves) and feeds up to
// two Q-tiles. LDS layout [k-half][row][32] keeps the m97 64-B-stride fragment reads.
// Q,K: [B*H][S][64]; Vt: [B*H][64][S]; O: [B][S][1024]
__global__ __launch_bounds__(256, 2)
void attn_kernel(const u16* __restrict__ Q, const u16* __restrict__ Kg,
                 const u16* __restrict__ Vt, u16* __restrict__ O)
{
    const int bh = blockIdx.x;            // fastest -> XCD = bh % 8
    const int pr = blockIdx.y;            // 0..15
    const int qta = pr, qtb = 31 - pr;
    const int t = threadIdx.x, wave = t >> 6, lane = t & 63;
    const int lr = lane & 15, quad = lane >> 4;

    __shared__ __align__(16) u16 Ks[4096];        // [2][64][32]
    __shared__ __align__(16) u16 Vs[4096];        // [2][64][32]
    __shared__ __align__(16) u16 Ps[4][16*72];    // wave-private P round-trip

    const size_t qkbase = (size_t)bh * (S_LEN*HD);
    const int b = bh >> 4, h = bh & 15;
    u16* Pw = Ps[wave];
    const f32x4 fzero = {0.f, 0.f, 0.f, 0.f};

    const u16* qpa = Q + qkbase + (size_t)(qta*64 + wave*16 + lr)*HD + quad*8;
    const u16* qpb = Q + qkbase + (size_t)(qtb*64 + wave*16 + lr)*HD + quad*8;
    bf16x8 qa0 = *(const bf16x8*)qpa, qa1 = *(const bf16x8*)(qpa + 32);
    bf16x8 qb0 = *(const bf16x8*)qpb, qb1 = *(const bf16x8*)(qpb + 32);

    f32x4 oa[4], ob[4];
    float la[4], lb[4];
    #pragma unroll
    for (int dt = 0; dt < 4; ++dt) { oa[dt] = fzero; ob[dt] = fzero; }
    #pragma unroll
    for (int r = 0; r < 4; ++r) { la[r] = 0.f; lb[r] = 0.f; }

    const u16* gK = Kg + qkbase + (size_t)(wave*16 + (lane>>2))*HD + (lane&3)*8;
    const u16* gV = Vt + qkbase + (size_t)(wave*16 + (lane>>2))*S_LEN + (lane&3)*8;
    u16* lK = Ks + wave*512;
    u16* lV = Vs + wave*512;

    const int qrow_qa = qta*64 + wave*16 + quad*4;
    const int qrow_qb = qtb*64 + wave*16 + quad*4;

    for (int kb = 0; kb <= qtb; ++kb) {
        __syncthreads();
        load_lds16(gK + (size_t)kb*4096,      lK);
        load_lds16(gK + (size_t)kb*4096 + 32, lK + 2048);
        load_lds16(gV + kb*64,                lV);
        load_lds16(gV + kb*64 + 32,           lV + 2048);
        __syncthreads();

        #pragma unroll
        for (int tile = 0; tile < 2; ++tile) {
            const int qt = tile ? qta : qtb;
            if (tile && kb > qta) break;
            bf16x8 qf0 = tile ? qa0 : qb0;
            bf16x8 qf1 = tile ? qa1 : qb1;
            f32x4* oacc = tile ? oa : ob;
            float* lp   = tile ? la : lb;
            const int qrowq = tile ? qrow_qa : qrow_qb;

            f32x4 sc[4];
            #pragma unroll
            for (int kt2 = 0; kt2 < 4; ++kt2) {
                bf16x8 kf0 = *(const bf16x8*)&Ks[(kt2*16 + lr)*32 + quad*8];
                bf16x8 kf1 = *(const bf16x8*)&Ks[2048 + (kt2*16 + lr)*32 + quad*8];
                sc[kt2] = __builtin_amdgcn_mfma_f32_16x16x32_bf16(qf0, kf0, fzero, 0, 0, 0);
                sc[kt2] = __builtin_amdgcn_mfma_f32_16x16x32_bf16(qf1, kf1, sc[kt2], 0, 0, 0);
            }
            const bool diag = (kb == qt);
            #pragma unroll
            for (int r = 0; r < 4; ++r) {
                #pragma unroll
                for (int kt2 = 0; kt2 < 4; ++kt2) {
                    int kcol = kb*64 + kt2*16 + lr;
                    float p = (!diag || kcol <= qrowq + r) ? __expf(fminf(sc[kt2][r]*0.125f, 30.f)) : 0.f;
                    lp[r] += p;
                    Pw[(quad*4 + r)*72 + kt2*16 + lr] = f2b(p);
                }
            }
            bf16x8 pf0 = *(const bf16x8*)&Pw[lr*72 + quad*8];
            bf16x8 pf1 = *(const bf16x8*)&Pw[lr*72 + 32 + quad*8];
            #pragma unroll
            for (int dt = 0; dt < 4; ++dt) {
                bf16x8 vf0 = *(const bf16x8*)&Vs[(dt*16 + lr)*32 + quad*8];
                bf16x8 vf1 = *(const bf16x8*)&Vs[2048 + (dt*16 + lr)*32 + quad*8];
                oacc[dt] = __builtin_amdgcn_mfma_f32_16x16x32_bf16(pf0, vf0, oacc[dt], 0, 0, 0);
                oacc[dt] = __builtin_amdgcn_mfma_f32_16x16x32_bf16(pf1, vf1, oacc[dt], 0, 0, 0);
            }
        }
    }

    #pragma unroll
    for (int tile = 0; tile < 2; ++tile) {
        const int qt = tile ? qta : qtb;
        f32x4* oacc = tile ? oa : ob;
        float* lp   = tile ? la : lb;
        #pragma unroll
        for (int r = 0; r < 4; ++r) {
            float v = lp[r];
            v += __shfl_xor(v, 1, 64); v += __shfl_xor(v, 2, 64);
            v += __shfl_xor(v, 4, 64); v += __shfl_xor(v, 8, 64);
            lp[r] = 1.0f / fmaxf(v, 1e-20f);
        }
        #pragma unroll
        for (int dt = 0; dt < 4; ++dt)
            #pragma unroll
            for (int r = 0; r < 4; ++r)
                Pw[(quad*4 + r)*64 + dt*16 + lr] = f2b(oacc[dt][r] * lp[r]);

        const int q = lane >> 2, d0 = (lane & 3)*16;
        u16* dst = O + ((size_t)(b*S_LEN + qt*64 + wave*16 + q))*EMB + h*HD + d0;
        *(uint4*)(dst)     = *(uint4*)&Pw[q*64 + d0];
        *(uint4*)(dst + 8) = *(uint4*)&Pw[q*64 + d0 + 8];
    }
}

// ---------------------------------------------------------------- launch
extern "C" void kernel_launch(void* const* d_in, const int* in_sizes, int n_in,
                              void* d_out, int out_size, void* d_ws, size_t ws_size,
                              hipStream_t stream)
{
    (void)in_sizes; (void)n_in; (void)out_size; (void)ws_size;
    const float* x    = (const float*)d_in[0];
    // d_in[1] = mask: causal tril, handled analytically
    const float* ln1g = (const float*)d_in[2];
    const float* ln1b = (const float*)d_in[3];
    const float* wq = (const float*)d_in[4];  const float* bq = (const float*)d_in[5];
    const float* wk = (const float*)d_in[6];  const float* bk = (const float*)d_in[7];
    const float* wv = (const float*)d_in[8];  const float* bv = (const float*)d_in[9];
    const float* wo = (const float*)d_in[10]; const float* bo = (const float*)d_in[11];
    const float* ln2g = (const float*)d_in[12]; const float* ln2b = (const float*)d_in[13];
    const float* w1 = (const float*)d_in[14]; const float* b1 = (const float*)d_in[15];
    const float* w2 = (const float*)d_in[16]; const float* b2 = (const float*)d_in[17];

    u16* ws = (u16*)d_ws;
    const size_t M1 = 1u << 20;             // 1M u16 elements (2 MB)
    u16* wqkvT = ws + 0*M1;                 // bf16 [3072][1024] = wqT|wkT|wvT contiguous
    u16* wqT = ws + 0*M1;
    u16* wkT = ws + 1*M1;
    u16* wvT = ws + 2*M1;
    u16* woT = ws + 3*M1;
    u16* w2T = ws + 0*M1;                   // bf16 [1024][4096], transposed AFTER wo-gemm
    u16* w1T = ws + 4*M1;                   // bf16 [4096][1024]
    u16* h0  = ws + 8*M1;                   // bf16 ln out (reused for ln2 out)
    u16* qb  = ws + 12*M1;                  // bf16 [B,H,S,D]
    u16* kb  = ws + 16*M1;                  // bf16 [B,H,S,D]
    u16* vT  = ws + 20*M1;                  // bf16 [B,H,D,S]
    u16* ao  = ws + 24*M1;                  // bf16 attn out [B,S,E]
    u16* vb  = ws + 24*M1;                  // bf16 V [B,H,S,D] (dead before attn writes ao)
    u16* x1  = ws + 28*M1;                  // bf16 residual-1 out
    u16* fb  = ws + 12*M1;                  // bf16 MLP hidden, overlays q/k/v/ao (dead)

    dim3 blk(256);
    transpose_k<<<dim3(16,16), blk, 0, stream>>>(wq, wqT, EMB, EMB);
    transpose_k<<<dim3(16,16), blk, 0, stream>>>(wk, wkT, EMB, EMB);
    transpose_k<<<dim3(16,16), blk, 0, stream>>>(wv, wvT, EMB, EMB);
    transpose_k<<<dim3(16,16), blk, 0, stream>>>(wo, woT, EMB, EMB);
    transpose_k<<<dim3(64,16), blk, 0, stream>>>(w1, w1T, EMB, FF_DIM);

    ln_kernel<1><<<NROWS, blk, 0, stream>>>(x, ln1g, ln1b, h0);

    gemm_bt<5,0,0,128><<<dim3(24,32), blk, 0, stream>>>(h0, wqkvT, bq, bk, bv, nullptr,
                                                        qb, kb, vb, NROWS, 3072, EMB);

    vtrans<<<dim3(32,32), blk, 0, stream>>>(vb, vT);

    attn_kernel<<<dim3(32,16), blk, 0, stream>>>(qb, kb, vT, ao);

    gemm_bt<1,1,0,64><<<dim3(64,8), blk, 0, stream>>>(ao, woT, bo, nullptr, nullptr, x,
                                                      x1, nullptr, nullptr, NROWS, EMB, EMB);

    transpose_k<<<dim3(16,64), blk, 0, stream>>>(w2, w2T, FF_DIM, EMB);

    ln_kernel<0><<<NROWS, blk, 0, stream>>>(x1, ln2g, ln2b, h0);

    gemm_bt<2,0,0,128><<<dim3(32,32), blk, 0, stream>>>(h0, w1T, b1, nullptr, nullptr, nullptr,
                                                        fb, nullptr, nullptr, NROWS, FF_DIM, EMB);
    gemm_bt<1,0,1,64><<<dim3(64,8), blk, 0, stream>>>(fb, w2T, b2, nullptr, nullptr, x1,
                                                      d_out, nullptr, nullptr, NROWS, EMB, FF_DIM);
}